// Round 4
// baseline (454.096 us; speedup 1.0000x reference)
//
#include <hip/hip_runtime.h>
#include <hip/hip_bf16.h>
#include <hip/hip_fp16.h>
#include <math.h>

#define EPSN 1e-12f
#define NPB 256           // nodes per bucket
#define NPB_SHIFT 8
#define SRC_BITS 17       // N = 131072 = 2^17
#define SRC_MASK ((1 << SRC_BITS) - 1)
#define MAXB 1024
#define A2_EPT 16         // edges per thread in bucket_scatter
#define CAP 9216          // max edges per bucket staged in LDS (11 sigma over 8192)

union RowU { int4 v[2]; _Float16 h[16]; };

// ---------------- utility kernels ----------------

__global__ void zero_ints(int* p, int n) {
    int i = blockIdx.x * blockDim.x + threadIdx.x;
    if (i < n) p[i] = 0;
}

__global__ void init_out(float* out, const float* gb, int G) {
    int g = blockIdx.x * blockDim.x + threadIdx.x;
    if (g < G) out[g] = gb[0];
}

// v[c] = sum_j gather_w[j] * lin2_w[j][c]  (c<16);  v[16] = gather_w . lin2_b
__global__ void compute_v(const float* l2w, const float* l2b, const float* gw,
                          float* vbuf) {
    int t = threadIdx.x;
    if (t < 16) {
        float a = 0.f;
        for (int j = 0; j < 64; ++j) a = fmaf(gw[j], l2w[j * 16 + t], a);
        vbuf[t] = a;
    } else if (t == 16) {
        float a = 0.f;
        for (int j = 0; j < 64; ++j) a = fmaf(gw[j], l2b[j], a);
        vbuf[16] = a;
    }
}

// ---------------- lin1 + relu: h rows (fp16) + 1/norm ----------------
__global__ void lin1_relu_norm(const float* __restrict__ x,
                               const float* __restrict__ W1,
                               const float* __restrict__ b1,
                               _Float16* __restrict__ h1, float* __restrict__ invs1,
                               int N, int D) {
    __shared__ float Ws[16 * 75];
    __shared__ float Bs[16];
    for (int i = threadIdx.x; i < 16 * D; i += blockDim.x) Ws[i] = W1[i];
    if (threadIdx.x < 16) Bs[threadIdx.x] = b1[threadIdx.x];
    __syncthreads();

    int node = blockIdx.x * (blockDim.x >> 4) + (threadIdx.x >> 4);
    int c = threadIdx.x & 15;
    if (node >= N) return;

    const float* xr = x + (size_t)node * D;
    float acc = Bs[c];
    for (int k = 0; k < D; ++k) acc = fmaf(xr[k], Ws[c * D + k], acc);
    float h = fmaxf(acc, 0.f);

    float ss = h * h;
    ss += __shfl_xor(ss, 8);
    ss += __shfl_xor(ss, 4);
    ss += __shfl_xor(ss, 2);
    ss += __shfl_xor(ss, 1);
    float s = fmaxf(sqrtf(ss), EPSN);

    float hn = __shfl_xor(h, 1);
    if (!(c & 1)) {
        union { _Float16 hh[2]; int i; } u;
        u.hh[0] = (_Float16)h;
        u.hh[1] = (_Float16)hn;
        ((int*)h1)[node * 8 + (c >> 1)] = u.i;
    }
    if (c == 0) invs1[node] = 1.f / s;
}

// ---------------- bucketed CSR build ----------------

__global__ void bucket_count(const int* __restrict__ dst, int E,
                             int* __restrict__ gcount, int NB) {
    __shared__ int h[MAXB];
    for (int i = threadIdx.x; i < NB; i += blockDim.x) h[i] = 0;
    __syncthreads();
    for (int e = blockIdx.x * blockDim.x + threadIdx.x; e < E;
         e += gridDim.x * blockDim.x)
        atomicAdd(&h[dst[e] >> NPB_SHIFT], 1);
    __syncthreads();
    for (int i = threadIdx.x; i < NB; i += blockDim.x)
        if (h[i]) atomicAdd(&gcount[i], h[i]);
}

__global__ void bucket_scan(const int* __restrict__ gcount, int* __restrict__ gbase,
                            int* __restrict__ gcursor, int NB) {
    __shared__ int tmp[MAXB];
    int t = threadIdx.x;
    int v = (t < NB) ? gcount[t] : 0;
    tmp[t] = v;
    __syncthreads();
    for (int off = 1; off < MAXB; off <<= 1) {
        int u = (t >= off) ? tmp[t - off] : 0;
        __syncthreads();
        tmp[t] += u;
        __syncthreads();
    }
    if (t < NB) {
        int ex = tmp[t] - v;
        gbase[t] = ex;
        gcursor[t] = ex;
    }
    if (t == NB - 1) gbase[NB] = tmp[t];
}

__global__ void bucket_scatter(const int* __restrict__ src, const int* __restrict__ dst,
                               int E, int* __restrict__ gcursor,
                               int* __restrict__ packed, int NB) {
    __shared__ int h[MAXB];
    __shared__ int gpos[MAXB];
    for (int i = threadIdx.x; i < NB; i += blockDim.x) h[i] = 0;
    __syncthreads();
    int base = blockIdx.x * (blockDim.x * A2_EPT);
    int rs[A2_EPT], rd[A2_EPT], rr[A2_EPT];
#pragma unroll
    for (int k = 0; k < A2_EPT; ++k) {
        int e = base + k * blockDim.x + threadIdx.x;
        if (e < E) {
            rs[k] = src[e];
            rd[k] = dst[e];
            rr[k] = atomicAdd(&h[rd[k] >> NPB_SHIFT], 1);
        }
    }
    __syncthreads();
    for (int i = threadIdx.x; i < NB; i += blockDim.x) {
        int c = h[i];
        gpos[i] = c ? atomicAdd(&gcursor[i], c) : 0;
    }
    __syncthreads();
#pragma unroll
    for (int k = 0; k < A2_EPT; ++k) {
        int e = base + k * blockDim.x + threadIdx.x;
        if (e < E) {
            int b = rd[k] >> NPB_SHIFT;
            int dl = rd[k] & (NPB - 1);
            packed[gpos[b] + rr[k]] = (dl << SRC_BITS) | rs[k];
        }
    }
}

// Phase B: per-bucket build, staging the bucket in LDS so csr_src can be the
// SAME buffer as packed (in-place permutation). 256 threads per bucket.
__global__ void csr_build(int* __restrict__ edgebuf, const int* __restrict__ gbase,
                          int* __restrict__ deg, int* __restrict__ offs, int N) {
    __shared__ int stage[CAP];
    __shared__ int ldeg[NPB];
    __shared__ int lofs[NPB];
    int b = blockIdx.x;
    int t = threadIdx.x;
    int e0 = gbase[b], e1 = gbase[b + 1];
    int cnt = e1 - e0;
    if (cnt > CAP) cnt = CAP;  // statistically unreachable (11 sigma)
    ldeg[t] = 0;
    for (int i = t; i < cnt; i += NPB) stage[i] = edgebuf[e0 + i];
    __syncthreads();
    for (int i = t; i < cnt; i += NPB)
        atomicAdd(&ldeg[stage[i] >> SRC_BITS], 1);
    __syncthreads();
    int v = ldeg[t];
    lofs[t] = v;
    __syncthreads();
    for (int off = 1; off < NPB; off <<= 1) {
        int u = (t >= off) ? lofs[t - off] : 0;
        __syncthreads();
        lofs[t] += u;
        __syncthreads();
    }
    int ex = lofs[t] - v;  // exclusive
    int node = (b << NPB_SHIFT) + t;
    if (node < N) {
        deg[node] = v;
        offs[node] = e0 + ex;
    }
    __syncthreads();
    lofs[t] = ex;  // reuse as cursor
    __syncthreads();
    for (int i = t; i < cnt; i += NPB) {
        int p = stage[i];
        int pos = atomicAdd(&lofs[p >> SRC_BITS], 1);
        edgebuf[e0 + pos] = p & SRC_MASK;
    }
}

// ---------------- conv1: 1 lane per node ----------------
__global__ __launch_bounds__(256) void agnn_conv1(
    const _Float16* __restrict__ h1, const float* __restrict__ invs1,
    const int* __restrict__ offs, const int* __restrict__ deg,
    const int* __restrict__ csr, const float* __restrict__ beta_p,
    const float* __restrict__ vbuf,
    _Float16* __restrict__ h2, float2* __restrict__ sp2, int N) {
    int node = blockIdx.x * blockDim.x + threadIdx.x;
    if (node >= N) return;
    float beta = beta_p[0];
    const int4* rp = (const int4*)h1;
    RowU rd;
    rd.v[0] = rp[2 * node];
    rd.v[1] = rp[2 * node + 1];
    float hd[16];
#pragma unroll
    for (int k = 0; k < 16; ++k) hd[k] = (float)rd.h[k];
    float invsd = invs1[node];

    float dself = 0.f;
#pragma unroll
    for (int k = 0; k < 16; ++k) dself = fmaf(hd[k], hd[k], dself);
    float e0 = __expf(beta * dself * invsd * invsd);
    float denom = e0;
    float acc[16];
#pragma unroll
    for (int k = 0; k < 16; ++k) acc[k] = e0 * hd[k];

    int start = offs[node], cnt = deg[node];
    int i = 0;
    for (; i + 4 <= cnt; i += 4) {
        int j[4];
        RowU r[4];
        float sj[4];
#pragma unroll
        for (int u = 0; u < 4; ++u) j[u] = csr[start + i + u];
#pragma unroll
        for (int u = 0; u < 4; ++u) {
            r[u].v[0] = rp[2 * j[u]];
            r[u].v[1] = rp[2 * j[u] + 1];
            sj[u] = invs1[j[u]];
        }
#pragma unroll
        for (int u = 0; u < 4; ++u) {
            float d = 0.f;
            float hs[16];
#pragma unroll
            for (int k = 0; k < 16; ++k) {
                hs[k] = (float)r[u].h[k];
                d = fmaf(hd[k], hs[k], d);
            }
            float ee = __expf(beta * d * invsd * sj[u]);
            denom += ee;
#pragma unroll
            for (int k = 0; k < 16; ++k) acc[k] = fmaf(ee, hs[k], acc[k]);
        }
    }
    for (; i < cnt; ++i) {
        int j = csr[start + i];
        RowU r;
        r.v[0] = rp[2 * j];
        r.v[1] = rp[2 * j + 1];
        float sjv = invs1[j];
        float d = 0.f;
        float hs[16];
#pragma unroll
        for (int k = 0; k < 16; ++k) {
            hs[k] = (float)r.h[k];
            d = fmaf(hd[k], hs[k], d);
        }
        float ee = __expf(beta * d * invsd * sjv);
        denom += ee;
#pragma unroll
        for (int k = 0; k < 16; ++k) acc[k] = fmaf(ee, hs[k], acc[k]);
    }

    // epilogue: normalize row, project with v, emit fp16 row + (inv_s, p)
    float inv = 1.f / denom;
    float ss = 0.f, p = 0.f;
    RowU w;
#pragma unroll
    for (int k = 0; k < 16; ++k) {
        float o = acc[k] * inv;
        ss = fmaf(o, o, ss);
        p = fmaf(o, vbuf[k], p);
        w.h[k] = (_Float16)o;
    }
    float s2 = fmaxf(sqrtf(ss), EPSN);
    int4* wp = (int4*)h2;
    wp[2 * node] = w.v[0];
    wp[2 * node + 1] = w.v[1];
    sp2[node] = make_float2(1.f / s2, p);
}

// ---------------- conv2: 1 lane per node, scalar payload ----------------
__global__ __launch_bounds__(256) void agnn_conv2(
    const _Float16* __restrict__ h2, const float2* __restrict__ sp2,
    const int* __restrict__ offs, const int* __restrict__ deg,
    const int* __restrict__ csr, const float* __restrict__ beta_p,
    float* __restrict__ rbuf, int N) {
    int node = blockIdx.x * blockDim.x + threadIdx.x;
    if (node >= N) return;
    float beta = beta_p[0];
    const int4* rp = (const int4*)h2;
    RowU rd;
    rd.v[0] = rp[2 * node];
    rd.v[1] = rp[2 * node + 1];
    float hd[16];
#pragma unroll
    for (int k = 0; k < 16; ++k) hd[k] = (float)rd.h[k];
    float2 spd = sp2[node];
    float invsd = spd.x;

    float dself = 0.f;
#pragma unroll
    for (int k = 0; k < 16; ++k) dself = fmaf(hd[k], hd[k], dself);
    float e0 = __expf(beta * dself * invsd * invsd);
    float denom = e0;
    float acc = e0 * spd.y;

    int start = offs[node], cnt = deg[node];
    int i = 0;
    for (; i + 4 <= cnt; i += 4) {
        int j[4];
        RowU r[4];
        float2 sp[4];
#pragma unroll
        for (int u = 0; u < 4; ++u) j[u] = csr[start + i + u];
#pragma unroll
        for (int u = 0; u < 4; ++u) {
            r[u].v[0] = rp[2 * j[u]];
            r[u].v[1] = rp[2 * j[u] + 1];
            sp[u] = sp2[j[u]];
        }
#pragma unroll
        for (int u = 0; u < 4; ++u) {
            float d = 0.f;
#pragma unroll
            for (int k = 0; k < 16; ++k) d = fmaf(hd[k], (float)r[u].h[k], d);
            float ee = __expf(beta * d * invsd * sp[u].x);
            denom += ee;
            acc = fmaf(ee, sp[u].y, acc);
        }
    }
    for (; i < cnt; ++i) {
        int j = csr[start + i];
        RowU r;
        r.v[0] = rp[2 * j];
        r.v[1] = rp[2 * j + 1];
        float2 sp = sp2[j];
        float d = 0.f;
#pragma unroll
        for (int k = 0; k < 16; ++k) d = fmaf(hd[k], (float)r.h[k], d);
        float ee = __expf(beta * d * invsd * sp.x);
        denom += ee;
        acc = fmaf(ee, sp.y, acc);
    }
    rbuf[node] = acc / denom;
}

// ---------------- pooling: out[g] += r[n] + c0 ----------------
__global__ void pool_kernel(const float* __restrict__ r, const int* __restrict__ batch,
                            const float* __restrict__ vbuf, float* __restrict__ out,
                            int N) {
    int i = blockIdx.x * blockDim.x + threadIdx.x;
    if (i < N) atomicAdd(&out[batch[i]], r[i] + vbuf[16]);
}

// ---------------- launcher ----------------

extern "C" void kernel_launch(void* const* d_in, const int* in_sizes, int n_in,
                              void* d_out, int out_size, void* d_ws, size_t ws_size,
                              hipStream_t stream) {
    const float* x = (const float*)d_in[0];
    const int* edge_index = (const int*)d_in[1];
    const int* batch = (const int*)d_in[2];
    const float* lin1_w = (const float*)d_in[4];
    const float* lin1_b = (const float*)d_in[5];
    const float* beta1 = (const float*)d_in[6];
    const float* beta2 = (const float*)d_in[7];
    const float* lin2_w = (const float*)d_in[8];
    const float* lin2_b = (const float*)d_in[9];
    const float* gather_w = (const float*)d_in[10];
    const float* gather_b = (const float*)d_in[11];
    float* out = (float*)d_out;

    const int N = in_sizes[2];
    const int E = in_sizes[1] / 2;
    const int D = in_sizes[0] / N;  // 75
    const int G = out_size;
    const int NB = (N + NPB - 1) >> NPB_SHIFT;  // 512 buckets

    const int* src = edge_index;
    const int* dst = edge_index + E;

    // workspace carve (4-byte words); ~28 MB total, no aliasing.
    float* w = (float*)d_ws;
    _Float16* h1 = (_Float16*)w;         w += (size_t)N * 8;   // N*16 halves
    _Float16* h2 = (_Float16*)w;         w += (size_t)N * 8;
    float* invs1 = w;                    w += N;
    float2* sp2 = (float2*)w;            w += (size_t)N * 2;
    float* rbuf = w;                     w += N;
    float* vbuf = w;                     w += 32;
    int* deg = (int*)w;                  w += N;
    int* offs = (int*)w;                 w += N;
    int* edgebuf = (int*)w;              w += E;   // packed, then csr_src in place
    int* gcount = (int*)w;               w += MAXB;
    int* gbase = (int*)w;                w += MAXB + 1;
    int* gcursor = (int*)w;              w += MAXB;

    const int B = 256;
    dim3 gridNode16((N + (B / 16) - 1) / (B / 16));
    dim3 gridNode1((N + B - 1) / B);
    dim3 gridN((N + B - 1) / B);

    // ---- CSR build ----
    zero_ints<<<dim3((MAXB + B - 1) / B), B, 0, stream>>>(gcount, MAXB);
    bucket_count<<<dim3(1024), B, 0, stream>>>(dst, E, gcount, NB);
    bucket_scan<<<dim3(1), MAXB, 0, stream>>>(gcount, gbase, gcursor, NB);
    bucket_scatter<<<dim3((E + B * A2_EPT - 1) / (B * A2_EPT)), B, 0, stream>>>(
        src, dst, E, gcursor, edgebuf, NB);
    csr_build<<<dim3(NB), NPB, 0, stream>>>(edgebuf, gbase, deg, offs, N);

    // ---- features ----
    lin1_relu_norm<<<gridNode16, B, 0, stream>>>(x, lin1_w, lin1_b, h1, invs1, N, D);
    compute_v<<<dim3(1), 64, 0, stream>>>(lin2_w, lin2_b, gather_w, vbuf);

    agnn_conv1<<<gridNode1, B, 0, stream>>>(h1, invs1, offs, deg, edgebuf,
                                            beta1, vbuf, h2, sp2, N);
    agnn_conv2<<<gridNode1, B, 0, stream>>>(h2, sp2, offs, deg, edgebuf,
                                            beta2, rbuf, N);

    init_out<<<dim3((G + B - 1) / B), B, 0, stream>>>(out, gather_b, G);
    pool_kernel<<<gridN, B, 0, stream>>>(rbuf, batch, vbuf, out, N);
}

// Round 5
// 437.115 us; speedup vs baseline: 1.0388x; 1.0388x over previous
//
#include <hip/hip_runtime.h>
#include <hip/hip_bf16.h>
#include <hip/hip_fp16.h>
#include <math.h>

#define EPSN 1e-12f
#define NPB 512           // nodes per bucket
#define NPB_SHIFT 9
#define SRC_BITS 17       // N = 131072 = 2^17
#define SRC_MASK ((1 << SRC_BITS) - 1)
#define MAXB 1024
#define A2_EPT 32         // edges per thread in bucket_scatter (long runs)

union RowU { int4 v[2]; _Float16 h[16]; };

// ---------------- utility kernels ----------------

__global__ void zero_ints(int* p, int n) {
    int i = blockIdx.x * blockDim.x + threadIdx.x;
    if (i < n) p[i] = 0;
}

__global__ void init_out(float* out, const float* gb, int G) {
    int g = blockIdx.x * blockDim.x + threadIdx.x;
    if (g < G) out[g] = gb[0];
}

// v[c] = sum_j gather_w[j] * lin2_w[j][c]  (c<16);  v[16] = gather_w . lin2_b
__global__ void compute_v(const float* l2w, const float* l2b, const float* gw,
                          float* vbuf) {
    int t = threadIdx.x;
    if (t < 16) {
        float a = 0.f;
        for (int j = 0; j < 64; ++j) a = fmaf(gw[j], l2w[j * 16 + t], a);
        vbuf[t] = a;
    } else if (t == 16) {
        float a = 0.f;
        for (int j = 0; j < 64; ++j) a = fmaf(gw[j], l2b[j], a);
        vbuf[16] = a;
    }
}

// ---------------- lin1 + relu: h rows (fp16) + 1/norm ----------------
__global__ void lin1_relu_norm(const float* __restrict__ x,
                               const float* __restrict__ W1,
                               const float* __restrict__ b1,
                               _Float16* __restrict__ h1, float* __restrict__ invs1,
                               int N, int D) {
    __shared__ float Ws[16 * 75];
    __shared__ float Bs[16];
    for (int i = threadIdx.x; i < 16 * D; i += blockDim.x) Ws[i] = W1[i];
    if (threadIdx.x < 16) Bs[threadIdx.x] = b1[threadIdx.x];
    __syncthreads();

    int node = blockIdx.x * (blockDim.x >> 4) + (threadIdx.x >> 4);
    int c = threadIdx.x & 15;
    if (node >= N) return;

    const float* xr = x + (size_t)node * D;
    float acc = Bs[c];
    for (int k = 0; k < D; ++k) acc = fmaf(xr[k], Ws[c * D + k], acc);
    float h = fmaxf(acc, 0.f);

    float ss = h * h;
    ss += __shfl_xor(ss, 8);
    ss += __shfl_xor(ss, 4);
    ss += __shfl_xor(ss, 2);
    ss += __shfl_xor(ss, 1);
    float s = fmaxf(sqrtf(ss), EPSN);

    float hn = __shfl_xor(h, 1);
    if (!(c & 1)) {
        union { _Float16 hh[2]; int i; } u;
        u.hh[0] = (_Float16)h;
        u.hh[1] = (_Float16)hn;
        ((int*)h1)[node * 8 + (c >> 1)] = u.i;
    }
    if (c == 0) invs1[node] = 1.f / s;
}

// ---------------- bucketed CSR build ----------------

__global__ void bucket_count(const int* __restrict__ dst, int E,
                             int* __restrict__ gcount, int NB) {
    __shared__ int h[MAXB];
    for (int i = threadIdx.x; i < NB; i += blockDim.x) h[i] = 0;
    __syncthreads();
    for (int e = blockIdx.x * blockDim.x + threadIdx.x; e < E;
         e += gridDim.x * blockDim.x)
        atomicAdd(&h[dst[e] >> NPB_SHIFT], 1);
    __syncthreads();
    for (int i = threadIdx.x; i < NB; i += blockDim.x)
        if (h[i]) atomicAdd(&gcount[i], h[i]);
}

__global__ void bucket_scan(const int* __restrict__ gcount, int* __restrict__ gbase,
                            int* __restrict__ gcursor, int NB) {
    __shared__ int tmp[MAXB];
    int t = threadIdx.x;
    int v = (t < NB) ? gcount[t] : 0;
    tmp[t] = v;
    __syncthreads();
    for (int off = 1; off < MAXB; off <<= 1) {
        int u = (t >= off) ? tmp[t - off] : 0;
        __syncthreads();
        tmp[t] += u;
        __syncthreads();
    }
    if (t < NB) {
        int ex = tmp[t] - v;
        gbase[t] = ex;
        gcursor[t] = ex;
    }
    if (t == NB - 1) gbase[NB] = tmp[t];
}

__global__ __launch_bounds__(256) void bucket_scatter(
    const int* __restrict__ src, const int* __restrict__ dst,
    int E, int* __restrict__ gcursor, int* __restrict__ packed, int NB) {
    __shared__ int h[MAXB];
    __shared__ int gpos[MAXB];
    for (int i = threadIdx.x; i < NB; i += blockDim.x) h[i] = 0;
    __syncthreads();
    int base = blockIdx.x * (blockDim.x * A2_EPT);
    int rs[A2_EPT], rd[A2_EPT], rr[A2_EPT];
#pragma unroll
    for (int k = 0; k < A2_EPT; ++k) {
        int e = base + k * blockDim.x + threadIdx.x;
        if (e < E) {
            rs[k] = src[e];
            rd[k] = dst[e];
            rr[k] = atomicAdd(&h[rd[k] >> NPB_SHIFT], 1);
        }
    }
    __syncthreads();
    for (int i = threadIdx.x; i < NB; i += blockDim.x) {
        int c = h[i];
        gpos[i] = c ? atomicAdd(&gcursor[i], c) : 0;
    }
    __syncthreads();
#pragma unroll
    for (int k = 0; k < A2_EPT; ++k) {
        int e = base + k * blockDim.x + threadIdx.x;
        if (e < E) {
            int b = rd[k] >> NPB_SHIFT;
            int dl = rd[k] & (NPB - 1);
            packed[gpos[b] + rr[k]] = (dl << SRC_BITS) | rs[k];
        }
    }
}

// Phase B: per-bucket local histogram + scan -> deg/offs/csr_src. 512 threads.
__global__ void csr_build(const int* __restrict__ packed, const int* __restrict__ gbase,
                          int* __restrict__ deg, int* __restrict__ offs,
                          int* __restrict__ csr_src, int N) {
    __shared__ int ldeg[NPB];
    __shared__ int lofs[NPB];
    int b = blockIdx.x;
    int t = threadIdx.x;
    int e0 = gbase[b], e1 = gbase[b + 1];
    int cnt = e1 - e0;
    ldeg[t] = 0;
    __syncthreads();
    for (int i = t; i < cnt; i += NPB)
        atomicAdd(&ldeg[packed[e0 + i] >> SRC_BITS], 1);
    __syncthreads();
    int v = ldeg[t];
    lofs[t] = v;
    __syncthreads();
    for (int off = 1; off < NPB; off <<= 1) {
        int u = (t >= off) ? lofs[t - off] : 0;
        __syncthreads();
        lofs[t] += u;
        __syncthreads();
    }
    int ex = lofs[t] - v;  // exclusive
    int node = (b << NPB_SHIFT) + t;
    if (node < N) {
        deg[node] = v;
        offs[node] = e0 + ex;
    }
    __syncthreads();
    lofs[t] = ex;  // reuse as cursor
    __syncthreads();
    for (int i = t; i < cnt; i += NPB) {
        int p = packed[e0 + i];
        int pos = atomicAdd(&lofs[p >> SRC_BITS], 1);
        csr_src[e0 + pos] = p & SRC_MASK;
    }
}

// ---------------- conv1: 1 lane per node ----------------
__global__ __launch_bounds__(256) void agnn_conv1(
    const _Float16* __restrict__ h1, const float* __restrict__ invs1,
    const int* __restrict__ offs, const int* __restrict__ deg,
    const int* __restrict__ csr, const float* __restrict__ beta_p,
    const float* __restrict__ vbuf,
    _Float16* __restrict__ h2, float2* __restrict__ sp2, int N) {
    int node = blockIdx.x * blockDim.x + threadIdx.x;
    if (node >= N) return;
    float beta = beta_p[0];
    const int4* rp = (const int4*)h1;
    RowU rd;
    rd.v[0] = rp[2 * node];
    rd.v[1] = rp[2 * node + 1];
    float hd[16];
#pragma unroll
    for (int k = 0; k < 16; ++k) hd[k] = (float)rd.h[k];
    float invsd = invs1[node];

    float dself = 0.f;
#pragma unroll
    for (int k = 0; k < 16; ++k) dself = fmaf(hd[k], hd[k], dself);
    float e0 = __expf(beta * dself * invsd * invsd);
    float denom = e0;
    float acc[16];
#pragma unroll
    for (int k = 0; k < 16; ++k) acc[k] = e0 * hd[k];

    int start = offs[node], cnt = deg[node];
    int i = 0;
    for (; i + 4 <= cnt; i += 4) {
        int j[4];
        RowU r[4];
        float sj[4];
#pragma unroll
        for (int u = 0; u < 4; ++u) j[u] = csr[start + i + u];
#pragma unroll
        for (int u = 0; u < 4; ++u) {
            r[u].v[0] = rp[2 * j[u]];
            r[u].v[1] = rp[2 * j[u] + 1];
            sj[u] = invs1[j[u]];
        }
#pragma unroll
        for (int u = 0; u < 4; ++u) {
            float d = 0.f;
            float hs[16];
#pragma unroll
            for (int k = 0; k < 16; ++k) {
                hs[k] = (float)r[u].h[k];
                d = fmaf(hd[k], hs[k], d);
            }
            float ee = __expf(beta * d * invsd * sj[u]);
            denom += ee;
#pragma unroll
            for (int k = 0; k < 16; ++k) acc[k] = fmaf(ee, hs[k], acc[k]);
        }
    }
    for (; i < cnt; ++i) {
        int j = csr[start + i];
        RowU r;
        r.v[0] = rp[2 * j];
        r.v[1] = rp[2 * j + 1];
        float sjv = invs1[j];
        float d = 0.f;
        float hs[16];
#pragma unroll
        for (int k = 0; k < 16; ++k) {
            hs[k] = (float)r.h[k];
            d = fmaf(hd[k], hs[k], d);
        }
        float ee = __expf(beta * d * invsd * sjv);
        denom += ee;
#pragma unroll
        for (int k = 0; k < 16; ++k) acc[k] = fmaf(ee, hs[k], acc[k]);
    }

    // epilogue: normalize row, project with v, emit fp16 row + (inv_s, p)
    float inv = 1.f / denom;
    float ss = 0.f, p = 0.f;
    RowU w;
#pragma unroll
    for (int k = 0; k < 16; ++k) {
        float o = acc[k] * inv;
        ss = fmaf(o, o, ss);
        p = fmaf(o, vbuf[k], p);
        w.h[k] = (_Float16)o;
    }
    float s2 = fmaxf(sqrtf(ss), EPSN);
    int4* wp = (int4*)h2;
    wp[2 * node] = w.v[0];
    wp[2 * node + 1] = w.v[1];
    sp2[node] = make_float2(1.f / s2, p);
}

// ---------------- conv2: 1 lane per node, scalar payload ----------------
__global__ __launch_bounds__(256) void agnn_conv2(
    const _Float16* __restrict__ h2, const float2* __restrict__ sp2,
    const int* __restrict__ offs, const int* __restrict__ deg,
    const int* __restrict__ csr, const float* __restrict__ beta_p,
    float* __restrict__ rbuf, int N) {
    int node = blockIdx.x * blockDim.x + threadIdx.x;
    if (node >= N) return;
    float beta = beta_p[0];
    const int4* rp = (const int4*)h2;
    RowU rd;
    rd.v[0] = rp[2 * node];
    rd.v[1] = rp[2 * node + 1];
    float hd[16];
#pragma unroll
    for (int k = 0; k < 16; ++k) hd[k] = (float)rd.h[k];
    float2 spd = sp2[node];
    float invsd = spd.x;

    float dself = 0.f;
#pragma unroll
    for (int k = 0; k < 16; ++k) dself = fmaf(hd[k], hd[k], dself);
    float e0 = __expf(beta * dself * invsd * invsd);
    float denom = e0;
    float acc = e0 * spd.y;

    int start = offs[node], cnt = deg[node];
    int i = 0;
    for (; i + 4 <= cnt; i += 4) {
        int j[4];
        RowU r[4];
        float2 sp[4];
#pragma unroll
        for (int u = 0; u < 4; ++u) j[u] = csr[start + i + u];
#pragma unroll
        for (int u = 0; u < 4; ++u) {
            r[u].v[0] = rp[2 * j[u]];
            r[u].v[1] = rp[2 * j[u] + 1];
            sp[u] = sp2[j[u]];
        }
#pragma unroll
        for (int u = 0; u < 4; ++u) {
            float d = 0.f;
#pragma unroll
            for (int k = 0; k < 16; ++k) d = fmaf(hd[k], (float)r[u].h[k], d);
            float ee = __expf(beta * d * invsd * sp[u].x);
            denom += ee;
            acc = fmaf(ee, sp[u].y, acc);
        }
    }
    for (; i < cnt; ++i) {
        int j = csr[start + i];
        RowU r;
        r.v[0] = rp[2 * j];
        r.v[1] = rp[2 * j + 1];
        float2 sp = sp2[j];
        float d = 0.f;
#pragma unroll
        for (int k = 0; k < 16; ++k) d = fmaf(hd[k], (float)r.h[k], d);
        float ee = __expf(beta * d * invsd * sp.x);
        denom += ee;
        acc = fmaf(ee, sp.y, acc);
    }
    rbuf[node] = acc / denom;
}

// ---------------- pooling: out[g] += r[n] + c0 ----------------
__global__ void pool_kernel(const float* __restrict__ r, const int* __restrict__ batch,
                            const float* __restrict__ vbuf, float* __restrict__ out,
                            int N) {
    int i = blockIdx.x * blockDim.x + threadIdx.x;
    if (i < N) atomicAdd(&out[batch[i]], r[i] + vbuf[16]);
}

// ---------------- launcher ----------------

extern "C" void kernel_launch(void* const* d_in, const int* in_sizes, int n_in,
                              void* d_out, int out_size, void* d_ws, size_t ws_size,
                              hipStream_t stream) {
    const float* x = (const float*)d_in[0];
    const int* edge_index = (const int*)d_in[1];
    const int* batch = (const int*)d_in[2];
    const float* lin1_w = (const float*)d_in[4];
    const float* lin1_b = (const float*)d_in[5];
    const float* beta1 = (const float*)d_in[6];
    const float* beta2 = (const float*)d_in[7];
    const float* lin2_w = (const float*)d_in[8];
    const float* lin2_b = (const float*)d_in[9];
    const float* gather_w = (const float*)d_in[10];
    const float* gather_b = (const float*)d_in[11];
    float* out = (float*)d_out;

    const int N = in_sizes[2];
    const int E = in_sizes[1] / 2;
    const int D = in_sizes[0] / N;  // 75
    const int G = out_size;
    const int NB = (N + NPB - 1) >> NPB_SHIFT;  // 256 buckets

    const int* src = edge_index;
    const int* dst = edge_index + E;

    // workspace carve (4-byte words); ~45 MB total, no aliasing.
    float* w = (float*)d_ws;
    _Float16* h1 = (_Float16*)w;         w += (size_t)N * 8;   // N*16 halves
    _Float16* h2 = (_Float16*)w;         w += (size_t)N * 8;
    float* invs1 = w;                    w += N;
    float2* sp2 = (float2*)w;            w += (size_t)N * 2;
    float* rbuf = w;                     w += N;
    float* vbuf = w;                     w += 32;
    int* deg = (int*)w;                  w += N;
    int* offs = (int*)w;                 w += N;
    int* packed = (int*)w;               w += E;
    int* csr_src = (int*)w;              w += E;
    int* gcount = (int*)w;               w += MAXB;
    int* gbase = (int*)w;                w += MAXB + 1;
    int* gcursor = (int*)w;              w += MAXB;

    const int B = 256;
    dim3 gridNode16((N + (B / 16) - 1) / (B / 16));
    dim3 gridNode1((N + B - 1) / B);
    dim3 gridN((N + B - 1) / B);

    // ---- CSR build ----
    zero_ints<<<dim3((MAXB + B - 1) / B), B, 0, stream>>>(gcount, MAXB);
    bucket_count<<<dim3(1024), B, 0, stream>>>(dst, E, gcount, NB);
    bucket_scan<<<dim3(1), MAXB, 0, stream>>>(gcount, gbase, gcursor, NB);
    bucket_scatter<<<dim3((E + B * A2_EPT - 1) / (B * A2_EPT)), B, 0, stream>>>(
        src, dst, E, gcursor, packed, NB);
    csr_build<<<dim3(NB), NPB, 0, stream>>>(packed, gbase, deg, offs, csr_src, N);

    // ---- features ----
    lin1_relu_norm<<<gridNode16, B, 0, stream>>>(x, lin1_w, lin1_b, h1, invs1, N, D);
    compute_v<<<dim3(1), 64, 0, stream>>>(lin2_w, lin2_b, gather_w, vbuf);

    agnn_conv1<<<gridNode1, B, 0, stream>>>(h1, invs1, offs, deg, csr_src,
                                            beta1, vbuf, h2, sp2, N);
    agnn_conv2<<<gridNode1, B, 0, stream>>>(h2, sp2, offs, deg, csr_src,
                                            beta2, rbuf, N);

    init_out<<<dim3((G + B - 1) / B), B, 0, stream>>>(out, gather_b, G);
    pool_kernel<<<gridN, B, 0, stream>>>(rbuf, batch, vbuf, out, N);
}